// Round 3
// baseline (299.890 us; speedup 1.0000x reference)
//
#include <hip/hip_runtime.h>
#include <math.h>

// SpiralNet bf16-MFMA v3: latency-oriented rewrite.
// - One 16-row tile per wave (6250 waves -> ~24 waves/CU schedulable).
// - 12 gather indices prefetched per lane as 3x int4 (48B row, always 16B aligned).
// - s-loop fully unrolled: all A-gathers / B-frag loads visible to the scheduler,
//   MFMAs overlap loads via ILP; __launch_bounds__(256,4) caps VGPR at 128.
// - No LDS, no barriers. WT stays L1/L2-hot (48-96 KB shared by all waves).

typedef __bf16 bf16;
typedef bf16  bf16x8 __attribute__((ext_vector_type(8)));
typedef float f32x4  __attribute__((ext_vector_type(4)));

// Fused weight transpose+convert: W[k][j] f32 -> WT[j][k] bf16 for all 3 layers.
__global__ __launch_bounds__(256)
void prep_all(const float* __restrict__ W0, const float* __restrict__ W1,
              const float* __restrict__ W2, bf16* __restrict__ WT0,
              bf16* __restrict__ WT1, bf16* __restrict__ WT2) {
    const int gid = blockIdx.x * 256 + threadIdx.x;
    if (gid < 384 * 64) {
        const int k = gid / 64, j = gid % 64;
        WT0[j * 384 + k] = (bf16)W0[gid];
    }
    const int g1 = gid - 384 * 64;
    if (g1 >= 0 && g1 < 768 * 64) {
        const int k = g1 / 64, j = g1 % 64;
        WT1[j * 768 + k] = (bf16)W1[g1];
    }
    const int g2 = gid - 384 * 64 - 768 * 64;
    if (g2 >= 0 && g2 < 768 * 32) {
        const int k = g2 / 32, j = g2 % 32;
        WT2[j * 768 + k] = (bf16)W2[g2];
    }
}

template<int CIN, int COUT, bool ELU, typename TIN, typename TOUT>
__global__ __launch_bounds__(256, 4)
void spiral_mfma(const TIN* __restrict__ h, const int* __restrict__ idx,
                 const bf16* __restrict__ WT, const float* __restrict__ bias,
                 TOUT* __restrict__ out, int n)
{
    constexpr int K  = 12 * CIN;
    constexpr int NT = COUT / 16;

    const int lane = threadIdx.x & 63;
    const int wave = threadIdx.x >> 6;
    const int m    = lane & 15;   // A row in tile / B col in tile
    const int quad = lane >> 4;   // k-octet selector
    const int i0   = (blockIdx.x * 4 + wave) * 16;
    if (i0 >= n) return;

    // Prefetch all 12 gather indices for this lane's row: 48 B, 16B-aligned.
    const int ir = (i0 + m < n) ? (i0 + m) : (n - 1);
    const int4* ip = reinterpret_cast<const int4*>(idx + (size_t)ir * 12);
    const int4 q0 = ip[0], q1 = ip[1], q2 = ip[2];
    const int rg[12] = {q0.x, q0.y, q0.z, q0.w,
                        q1.x, q1.y, q1.z, q1.w,
                        q2.x, q2.y, q2.z, q2.w};

    f32x4 acc[NT] = {};

    #pragma unroll
    for (int s = 0; s < 12; ++s) {
        const TIN* hrow = h + (size_t)rg[s] * CIN + quad * 8;
        #pragma unroll
        for (int c0 = 0; c0 < CIN; c0 += 32) {
            bf16x8 a;
            if constexpr (sizeof(TIN) == 2) {
                a = *reinterpret_cast<const bf16x8*>(hrow + c0);
            } else {
                const f32x4* p = reinterpret_cast<const f32x4*>(hrow + c0);
                const f32x4 f0 = p[0], f1 = p[1];
                a = (bf16x8){(bf16)f0[0], (bf16)f0[1], (bf16)f0[2], (bf16)f0[3],
                             (bf16)f1[0], (bf16)f1[1], (bf16)f1[2], (bf16)f1[3]};
            }
            const int kb = s * CIN + c0 + quad * 8;
            #pragma unroll
            for (int t = 0; t < NT; ++t) {
                const bf16x8 b = *reinterpret_cast<const bf16x8*>(
                    WT + (size_t)(t * 16 + m) * K + kb);
                acc[t] = __builtin_amdgcn_mfma_f32_16x16x32_bf16(a, b, acc[t], 0, 0, 0);
            }
        }
    }

    // Epilogue: D[row = quad*4+g][col = t*16+m], bias + optional ELU.
    #pragma unroll
    for (int t = 0; t < NT; ++t) {
        const int col = t * 16 + m;
        const float bv = bias[col];
        #pragma unroll
        for (int g = 0; g < 4; ++g) {
            const int row = i0 + quad * 4 + g;
            if (row < n) {
                float v = acc[t][g] + bv;
                if (ELU) v = (v > 0.f) ? v : (__expf(v) - 1.f);
                out[(size_t)row * COUT + col] = (TOUT)v;
            }
        }
    }
}

extern "C" void kernel_launch(void* const* d_in, const int* in_sizes, int n_in,
                              void* d_out, int out_size, void* d_ws, size_t ws_size,
                              hipStream_t stream) {
    const float* x   = (const float*)d_in[0];   // [N,32] fp32
    const int*   idx = (const int*)d_in[1];     // [N,12]
    const float* W0  = (const float*)d_in[2];   // [384,64]
    const float* b0  = (const float*)d_in[3];
    const float* W1  = (const float*)d_in[4];   // [768,64]
    const float* b1  = (const float*)d_in[5];
    const float* W2  = (const float*)d_in[6];   // [768,32]
    const float* b2  = (const float*)d_in[7];
    float* out = (float*)d_out;                 // [N,32] fp32

    const int n = in_sizes[0] / 32;             // N = 100000

    bf16* h1  = (bf16*)d_ws;                    // [n,64] bf16
    bf16* h2  = h1 + (size_t)n * 64;            // [n,64] bf16
    bf16* WT0 = h2 + (size_t)n * 64;            // [64,384]
    bf16* WT1 = WT0 + 64 * 384;                 // [64,768]
    bf16* WT2 = WT1 + 64 * 768;                 // [32,768]

    dim3 blk(256);
    const int prep_elems = 384 * 64 + 768 * 64 + 768 * 32;
    prep_all<<<(prep_elems + 255) / 256, blk, 0, stream>>>(W0, W1, W2, WT0, WT1, WT2);

    const int tiles = (n + 15) / 16;            // one 16-row tile per wave
    const int grid  = (tiles + 3) / 4;          // 4 waves per block
    spiral_mfma<32, 64, true,  float, bf16 ><<<grid, blk, 0, stream>>>(x,  idx, WT0, b0, h1,  n);
    spiral_mfma<64, 64, true,  bf16,  bf16 ><<<grid, blk, 0, stream>>>(h1, idx, WT1, b1, h2,  n);
    spiral_mfma<64, 32, false, bf16,  float><<<grid, blk, 0, stream>>>(h2, idx, WT2, b2, out, n);
}

// Round 4
// 173.925 us; speedup vs baseline: 1.7242x; 1.7242x over previous
//
#include <hip/hip_runtime.h>
#include <math.h>

// SpiralNet bf16-MFMA v4.
// Key fix vs R3: B-frag loads were 16-scattered-line instructions (WT rows 1536B
// apart) -> repack weights in FRAGMENT ORDER so each B load is uniform_base +
// lane*16B (coalesced 1KB burst). MR=2 row-tiles/wave balances B-amortization
// against occupancy (782 blocks ~ 3/CU ~ 12 waves/CU). x converted to bf16 once.

typedef __bf16 bf16;
typedef bf16  bf16x4 __attribute__((ext_vector_type(4)));
typedef bf16  bf16x8 __attribute__((ext_vector_type(8)));
typedef float f32x4  __attribute__((ext_vector_type(4)));

// Pack W [K][COUT] f32 into fragment-ordered bf16:
// frag f = (s*CC + cc)*NT + t ; within frag: lane (m=lane&15 -> col, quad=lane>>4
// -> k-octet), 8 elems. Element e of Bpack:
template<int CIN, int COUT>
__device__ inline void pack_one(const float* __restrict__ W, bf16* __restrict__ BP, int e) {
    constexpr int NT = COUT / 16, CC = CIN / 32;
    const int f = e >> 9, r = e & 511, lane = r >> 3, j = r & 7;
    const int t = f % NT, cc = (f / NT) % CC, s = f / (NT * CC);
    const int col = t * 16 + (lane & 15);
    const int k   = s * CIN + cc * 32 + (lane >> 4) * 8 + j;
    BP[e] = (bf16)W[k * COUT + col];
}

__global__ __launch_bounds__(256)
void prep_all(const float* __restrict__ x, bf16* __restrict__ xb,
              const float* __restrict__ W0, const float* __restrict__ W1,
              const float* __restrict__ W2, bf16* __restrict__ B0,
              bf16* __restrict__ B1, bf16* __restrict__ B2, int n)
{
    const int gid = blockIdx.x * 256 + threadIdx.x;
    const int e = gid * 4;
    if (e < n * 32) {
        const f32x4 v = *reinterpret_cast<const f32x4*>(x + e);
        bf16x4 o = {(bf16)v[0], (bf16)v[1], (bf16)v[2], (bf16)v[3]};
        *reinterpret_cast<bf16x4*>(xb + e) = o;
    }
    if (gid < 384 * 64)                       pack_one<32, 64>(W0, B0, gid);
    else if (gid < 384 * 64 + 768 * 64)       pack_one<64, 64>(W1, B1, gid - 384 * 64);
    else if (gid < 384 * 64 + 768 * 64 + 768 * 32)
                                              pack_one<64, 32>(W2, B2, gid - 384 * 64 - 768 * 64);
}

template<int CIN, int COUT, bool ELU, typename TOUT>
__global__ __launch_bounds__(256, 3)
void spiral_mfma(const bf16* __restrict__ h, const int* __restrict__ idx,
                 const bf16* __restrict__ BP, const float* __restrict__ bias,
                 TOUT* __restrict__ out, int n)
{
    constexpr int CC = CIN / 32;   // 32-k chunks per spiral step
    constexpr int NT = COUT / 16;  // 16-col output tiles

    const int lane = threadIdx.x & 63;
    const int wave = threadIdx.x >> 6;
    const int m    = lane & 15;
    const int quad = lane >> 4;
    const int i0   = (blockIdx.x * 4 + wave) * 32;   // MR=2 tiles of 16 rows
    if (i0 >= n) return;

    // Prefetch both tiles' gather indices (48B/row, 16B-aligned).
    const int ir0 = min(i0 + m, n - 1);
    const int ir1 = min(i0 + 16 + m, n - 1);
    const int4* p0 = reinterpret_cast<const int4*>(idx + (size_t)ir0 * 12);
    const int4* p1 = reinterpret_cast<const int4*>(idx + (size_t)ir1 * 12);
    const int4 q00 = p0[0], q01 = p0[1], q02 = p0[2];
    const int4 q10 = p1[0], q11 = p1[1], q12 = p1[2];
    const int rg0[12] = {q00.x,q00.y,q00.z,q00.w, q01.x,q01.y,q01.z,q01.w, q02.x,q02.y,q02.z,q02.w};
    const int rg1[12] = {q10.x,q10.y,q10.z,q10.w, q11.x,q11.y,q11.z,q11.w, q12.x,q12.y,q12.z,q12.w};

    f32x4 acc0[NT] = {}, acc1[NT] = {};

    #pragma unroll
    for (int s = 0; s < 12; ++s) {
        #pragma unroll
        for (int cc = 0; cc < CC; ++cc) {
            const int co = cc * 32 + quad * 8;
            const bf16x8 a0 = *reinterpret_cast<const bf16x8*>(h + (size_t)rg0[s] * CIN + co);
            const bf16x8 a1 = *reinterpret_cast<const bf16x8*>(h + (size_t)rg1[s] * CIN + co);
            #pragma unroll
            for (int t = 0; t < NT; ++t) {
                // coalesced: wave-uniform base + lane*16B
                const bf16x8 b = *reinterpret_cast<const bf16x8*>(
                    BP + ((size_t)((s * CC + cc) * NT + t) * 64 + lane) * 8);
                acc0[t] = __builtin_amdgcn_mfma_f32_16x16x32_bf16(a0, b, acc0[t], 0, 0, 0);
                acc1[t] = __builtin_amdgcn_mfma_f32_16x16x32_bf16(a1, b, acc1[t], 0, 0, 0);
            }
        }
    }

    // Epilogue: D[row = quad*4+g][col = t*16+m]; n%16==0 so tiles are all-or-none.
    #pragma unroll
    for (int t = 0; t < NT; ++t) {
        const int col = t * 16 + m;
        const float bv = bias[col];
        #pragma unroll
        for (int g = 0; g < 4; ++g) {
            {
                const int row = i0 + quad * 4 + g;
                float v = acc0[t][g] + bv;
                if (ELU) v = (v > 0.f) ? v : (__expf(v) - 1.f);
                out[(size_t)row * COUT + col] = (TOUT)v;
            }
            if (i0 + 16 < n) {
                const int row = i0 + 16 + quad * 4 + g;
                float v = acc1[t][g] + bv;
                if (ELU) v = (v > 0.f) ? v : (__expf(v) - 1.f);
                out[(size_t)row * COUT + col] = (TOUT)v;
            }
        }
    }
}

extern "C" void kernel_launch(void* const* d_in, const int* in_sizes, int n_in,
                              void* d_out, int out_size, void* d_ws, size_t ws_size,
                              hipStream_t stream) {
    const float* x   = (const float*)d_in[0];   // [N,32] fp32
    const int*   idx = (const int*)d_in[1];     // [N,12]
    const float* W0  = (const float*)d_in[2];   // [384,64]
    const float* b0  = (const float*)d_in[3];
    const float* W1  = (const float*)d_in[4];   // [768,64]
    const float* b1  = (const float*)d_in[5];
    const float* W2  = (const float*)d_in[6];   // [768,32]
    const float* b2  = (const float*)d_in[7];
    float* out = (float*)d_out;                 // [N,32] fp32

    const int n = in_sizes[0] / 32;             // N = 100000

    bf16* xb = (bf16*)d_ws;                     // [n,32]
    bf16* h1 = xb + (size_t)n * 32;             // [n,64]
    bf16* h2 = h1 + (size_t)n * 64;             // [n,64]
    bf16* B0 = h2 + (size_t)n * 64;             // 384*64
    bf16* B1 = B0 + 384 * 64;                   // 768*64
    bf16* B2 = B1 + 768 * 64;                   // 768*32

    dim3 blk(256);
    const int prep_threads = n * 8;             // n*32/4 elems per thread >= 98304 pack threads
    prep_all<<<(prep_threads + 255) / 256, blk, 0, stream>>>(x, xb, W0, W1, W2, B0, B1, B2, n);

    const int grid = (n + 127) / 128;           // 4 waves x 32 rows per block
    spiral_mfma<32, 64, true,  bf16 ><<<grid, blk, 0, stream>>>(xb, idx, B0, b0, h1,  n);
    spiral_mfma<64, 64, true,  bf16 ><<<grid, blk, 0, stream>>>(h1, idx, B1, b1, h2,  n);
    spiral_mfma<64, 32, false, float><<<grid, blk, 0, stream>>>(h2, idx, B2, b2, out, n);
}